// Round 1
// baseline (6763.384 us; speedup 1.0000x reference)
//
#include <hip/hip_runtime.h>
#include <hip/hip_bf16.h>
#include <cstdint>
#include <cstddef>

#define B_  256
#define N_  128
#define D_  1024
#define H_  4096
#define K1_ 819
#define K2_ 3276

// ---------------------------------------------------------------------------
// scores1[b,c] = sum_n x[b,n,c] * ws1[n]   (bias omitted: constant shift does
// not change top-k selection). fp64 accumulation, sequential n order.
// ---------------------------------------------------------------------------
__global__ __launch_bounds__(256) void scores1_kernel(const float* __restrict__ x,
                                                      const float* __restrict__ ws1,
                                                      float* __restrict__ scores1) {
  int b = blockIdx.x, t = threadIdx.x;
  __shared__ float w[N_];
  if (t < N_) w[t] = ws1[t];
  __syncthreads();
  const float* xb = x + (size_t)b * N_ * D_;
  double a0 = 0, a1 = 0, a2 = 0, a3 = 0;
  for (int n = 0; n < N_; ++n) {
    double wv = (double)w[n];
    const float* r = xb + (size_t)n * D_ + t;
    a0 += (double)r[0]   * wv;
    a1 += (double)r[256] * wv;
    a2 += (double)r[512] * wv;
    a3 += (double)r[768] * wv;
  }
  float* s = scores1 + (size_t)b * D_ + t;
  s[0]   = (float)a0;
  s[256] = (float)a1;
  s[512] = (float)a2;
  s[768] = (float)a3;
}

// ---------------------------------------------------------------------------
// Top-K per row via 8-bit radix select on order-preserving uint keys, then
// index-ordered compaction (ties kept by smallest index, matching top_k then
// sort). One block (256 threads) per batch row. C in {1024, 4096}.
// ---------------------------------------------------------------------------
__global__ __launch_bounds__(256) void topk_kernel(const float* __restrict__ scores,
                                                   int C, int K,
                                                   int* __restrict__ idx_out) {
  int b = blockIdx.x, t = threadIdx.x;
  __shared__ unsigned keys[4096];
  __shared__ unsigned hist[256];
  __shared__ unsigned sbuf[256];
  __shared__ unsigned s_sel, s_want, s_bgt, s_beq;

  for (int c = t; c < C; c += 256) {
    unsigned u = __float_as_uint(scores[(size_t)b * C + c]);
    keys[c] = u ^ ((u & 0x80000000u) ? 0xFFFFFFFFu : 0x80000000u);
  }
  if (t == 0) { s_want = (unsigned)K; s_bgt = 0u; s_beq = 0u; }
  __syncthreads();

  unsigned prefix = 0;
  for (int shift = 24; shift >= 0; shift -= 8) {
    hist[t] = 0u;
    __syncthreads();
    unsigned mask = (shift == 24) ? 0u : (0xFFFFFFFFu << (shift + 8));
    for (int c = t; c < C; c += 256) {
      unsigned k = keys[c];
      if ((k & mask) == (prefix & mask))
        atomicAdd(&hist[(k >> shift) & 0xFFu], 1u);
    }
    __syncthreads();
    if (t == 0) {
      unsigned want = s_want, cum = 0u, sel = 0u;
      for (int d = 255; d >= 0; --d) {
        cum += hist[d];
        if (cum >= want) { sel = (unsigned)d; s_want = want - (cum - hist[d]); break; }
      }
      s_sel = sel;
    }
    __syncthreads();
    prefix |= (s_sel << shift);
  }
  unsigned kth = prefix;            // exact K-th largest key
  unsigned n_eq_keep = s_want;      // how many keys == kth to keep (by index order)
  __syncthreads();

  int nch = C >> 8;
  for (int ch = 0; ch < nch; ++ch) {
    int c = (ch << 8) + t;
    unsigned k = keys[c];
    unsigned gt = (k > kth) ? 1u : 0u;
    unsigned eq = (k == kth) ? 1u : 0u;
    unsigned val = gt | (eq << 16);
    sbuf[t] = val;
    __syncthreads();
    unsigned incl = val;
    for (int off = 1; off < 256; off <<= 1) {
      unsigned o = (t >= off) ? sbuf[t - off] : 0u;
      __syncthreads();
      incl += o;
      sbuf[t] = incl;
      __syncthreads();
    }
    unsigned excl = incl - val;
    unsigned gt_ex = excl & 0xFFFFu, eq_ex = excl >> 16;
    unsigned base_gt = s_bgt, base_eq = s_beq;
    unsigned eq_before = base_eq + eq_ex;
    bool keep = (gt != 0u) || ((eq != 0u) && (eq_before < n_eq_keep));
    unsigned kept_eq_before = (eq_before < n_eq_keep) ? eq_before : n_eq_keep;
    unsigned pos = base_gt + gt_ex + kept_eq_before;
    if (keep) idx_out[(size_t)b * K + pos] = c;
    __syncthreads();
    if (t == 255) {
      s_bgt = base_gt + (incl & 0xFFFFu);
      s_beq = base_eq + (incl >> 16);
    }
    __syncthreads();
  }
}

// ---------------------------------------------------------------------------
// GEMM1 fused: h[b,n,hc] = relu( sum_k x[b,n,idx1[b,k]] * W1[hc,k] + b1[hc] )
// stored as bf16; scores2[b,hc] = sum_n h_fp32[b,n,hc] * ws2[n] computed in
// the epilogue from fp32 values (each block owns all 128 n-rows for its 128
// hc-channels, so no atomics needed).
// Tile: 128(n) x 128(hc), BK=8, 256 threads, 8x8 per thread, fp32 VALU.
// ---------------------------------------------------------------------------
__global__ __launch_bounds__(256) void gemm1_kernel(const float* __restrict__ x,
                                                    const int* __restrict__ idx1,
                                                    const float* __restrict__ W1,
                                                    const float* __restrict__ b1,
                                                    const float* __restrict__ ws2,
                                                    __hip_bfloat16* __restrict__ h,
                                                    float* __restrict__ scores2) {
  int b = blockIdx.y;
  int hc0 = blockIdx.x * 128;
  int t = threadIdx.x;
  int tx = t & 15, ty = t >> 4;
  __shared__ float As[8][128];
  __shared__ float Bs[8][128];
  __shared__ float wn[128];
  __shared__ double red[16][128];
  if (t < 128) wn[t] = ws2[t];

  float acc[8][8];
#pragma unroll
  for (int i = 0; i < 8; ++i)
#pragma unroll
    for (int j = 0; j < 8; ++j) acc[i][j] = 0.f;

  const int kq = t & 7;   // k within tile for staging
  const int rr = t >> 3;  // base row (n or hc) for staging: rr, rr+32, rr+64, rr+96
  const float* xb = x + (size_t)b * N_ * D_;
  const int* idxb = idx1 + (size_t)b * K1_;
  const int ntile = (K1_ + 7) / 8;  // 103

  for (int kt = 0; kt < ntile; ++kt) {
    int kg = kt * 8 + kq;
    bool kv = kg < K1_;
    int id = kv ? idxb[kg] : 0;
    float a0 = kv ? xb[(size_t)(rr     ) * D_ + id] : 0.f;
    float a1 = kv ? xb[(size_t)(rr + 32) * D_ + id] : 0.f;
    float a2 = kv ? xb[(size_t)(rr + 64) * D_ + id] : 0.f;
    float a3 = kv ? xb[(size_t)(rr + 96) * D_ + id] : 0.f;
    float bv0 = kv ? W1[(size_t)(hc0 + rr     ) * K1_ + kg] : 0.f;
    float bv1 = kv ? W1[(size_t)(hc0 + rr + 32) * K1_ + kg] : 0.f;
    float bv2 = kv ? W1[(size_t)(hc0 + rr + 64) * K1_ + kg] : 0.f;
    float bv3 = kv ? W1[(size_t)(hc0 + rr + 96) * K1_ + kg] : 0.f;
    __syncthreads();
    As[kq][rr] = a0; As[kq][rr + 32] = a1; As[kq][rr + 64] = a2; As[kq][rr + 96] = a3;
    Bs[kq][rr] = bv0; Bs[kq][rr + 32] = bv1; Bs[kq][rr + 64] = bv2; Bs[kq][rr + 96] = bv3;
    __syncthreads();
#pragma unroll
    for (int kk = 0; kk < 8; ++kk) {
      float av[8], bv[8];
      *(float4*)&av[0] = *(const float4*)&As[kk][ty * 8];
      *(float4*)&av[4] = *(const float4*)&As[kk][ty * 8 + 4];
      *(float4*)&bv[0] = *(const float4*)&Bs[kk][tx * 8];
      *(float4*)&bv[4] = *(const float4*)&Bs[kk][tx * 8 + 4];
#pragma unroll
      for (int r = 0; r < 8; ++r)
#pragma unroll
        for (int c2 = 0; c2 < 8; ++c2)
          acc[r][c2] += av[r] * bv[c2];
    }
  }

  // epilogue: bias + relu, bf16 store, fp64 scores2 partials
  float bias[8];
#pragma unroll
  for (int c2 = 0; c2 < 8; ++c2) bias[c2] = b1[hc0 + tx * 8 + c2];
  double p[8];
#pragma unroll
  for (int c2 = 0; c2 < 8; ++c2) p[c2] = 0.0;
#pragma unroll
  for (int r = 0; r < 8; ++r) {
    int n = ty * 8 + r;
    double wv = (double)wn[n];
    union { __hip_bfloat16 us[8]; uint4 v; } pk;
#pragma unroll
    for (int c2 = 0; c2 < 8; ++c2) {
      float v = acc[r][c2] + bias[c2];
      v = fmaxf(v, 0.f);
      pk.us[c2] = __float2bfloat16(v);
      p[c2] += (double)v * wv;
    }
    *(uint4*)&h[((size_t)(b * N_ + n)) * H_ + hc0 + tx * 8] = pk.v;
  }
#pragma unroll
  for (int c2 = 0; c2 < 8; ++c2) red[ty][tx * 8 + c2] = p[c2];
  __syncthreads();
  if (t < 128) {
    double s = 0.0;
#pragma unroll
    for (int q = 0; q < 16; ++q) s += red[q][t];  // ascending n order
    scores2[(size_t)b * H_ + hc0 + t] = (float)s;
  }
}

// ---------------------------------------------------------------------------
// GEMM2: out[b,n,d] = sum_k h[b,n,idx2[b,k]] * W2[d,k] + b2[d]
// Same tiling; A gathered from bf16 h.
// ---------------------------------------------------------------------------
__global__ __launch_bounds__(256) void gemm2_kernel(const __hip_bfloat16* __restrict__ h,
                                                    const int* __restrict__ idx2,
                                                    const float* __restrict__ W2,
                                                    const float* __restrict__ b2,
                                                    float* __restrict__ out) {
  int b = blockIdx.y;
  int d0 = blockIdx.x * 128;
  int t = threadIdx.x;
  int tx = t & 15, ty = t >> 4;
  __shared__ float As[8][128];
  __shared__ float Bs[8][128];

  float acc[8][8];
#pragma unroll
  for (int i = 0; i < 8; ++i)
#pragma unroll
    for (int j = 0; j < 8; ++j) acc[i][j] = 0.f;

  const int kq = t & 7;
  const int rr = t >> 3;
  const __hip_bfloat16* hb = h + (size_t)b * N_ * H_;
  const int* idxb = idx2 + (size_t)b * K2_;
  const int ntile = (K2_ + 7) / 8;  // 410

  for (int kt = 0; kt < ntile; ++kt) {
    int kg = kt * 8 + kq;
    bool kv = kg < K2_;
    int id = kv ? idxb[kg] : 0;
    float a0 = kv ? __bfloat162float(hb[(size_t)(rr     ) * H_ + id]) : 0.f;
    float a1 = kv ? __bfloat162float(hb[(size_t)(rr + 32) * H_ + id]) : 0.f;
    float a2 = kv ? __bfloat162float(hb[(size_t)(rr + 64) * H_ + id]) : 0.f;
    float a3 = kv ? __bfloat162float(hb[(size_t)(rr + 96) * H_ + id]) : 0.f;
    float bv0 = kv ? W2[(size_t)(d0 + rr     ) * K2_ + kg] : 0.f;
    float bv1 = kv ? W2[(size_t)(d0 + rr + 32) * K2_ + kg] : 0.f;
    float bv2 = kv ? W2[(size_t)(d0 + rr + 64) * K2_ + kg] : 0.f;
    float bv3 = kv ? W2[(size_t)(d0 + rr + 96) * K2_ + kg] : 0.f;
    __syncthreads();
    As[kq][rr] = a0; As[kq][rr + 32] = a1; As[kq][rr + 64] = a2; As[kq][rr + 96] = a3;
    Bs[kq][rr] = bv0; Bs[kq][rr + 32] = bv1; Bs[kq][rr + 64] = bv2; Bs[kq][rr + 96] = bv3;
    __syncthreads();
#pragma unroll
    for (int kk = 0; kk < 8; ++kk) {
      float av[8], bv[8];
      *(float4*)&av[0] = *(const float4*)&As[kk][ty * 8];
      *(float4*)&av[4] = *(const float4*)&As[kk][ty * 8 + 4];
      *(float4*)&bv[0] = *(const float4*)&Bs[kk][tx * 8];
      *(float4*)&bv[4] = *(const float4*)&Bs[kk][tx * 8 + 4];
#pragma unroll
      for (int r = 0; r < 8; ++r)
#pragma unroll
        for (int c2 = 0; c2 < 8; ++c2)
          acc[r][c2] += av[r] * bv[c2];
    }
  }

  float bias[8];
#pragma unroll
  for (int c2 = 0; c2 < 8; ++c2) bias[c2] = b2[d0 + tx * 8 + c2];
#pragma unroll
  for (int r = 0; r < 8; ++r) {
    int n = ty * 8 + r;
    float* op = out + ((size_t)(b * N_ + n)) * D_ + d0 + tx * 8;
    float4 o0, o1;
    o0.x = acc[r][0] + bias[0]; o0.y = acc[r][1] + bias[1];
    o0.z = acc[r][2] + bias[2]; o0.w = acc[r][3] + bias[3];
    o1.x = acc[r][4] + bias[4]; o1.y = acc[r][5] + bias[5];
    o1.z = acc[r][6] + bias[6]; o1.w = acc[r][7] + bias[7];
    *(float4*)op = o0;
    *(float4*)(op + 4) = o1;
  }
}

// ---------------------------------------------------------------------------
extern "C" void kernel_launch(void* const* d_in, const int* in_sizes, int n_in,
                              void* d_out, int out_size, void* d_ws, size_t ws_size,
                              hipStream_t stream) {
  (void)in_sizes; (void)n_in; (void)out_size; (void)ws_size;
  const float* x   = (const float*)d_in[0];
  const float* ws1 = (const float*)d_in[1];
  const float* W1  = (const float*)d_in[3];
  const float* b1  = (const float*)d_in[4];
  const float* ws2 = (const float*)d_in[5];
  const float* W2  = (const float*)d_in[7];
  const float* b2  = (const float*)d_in[8];
  float* out = (float*)d_out;

  char* p = (char*)d_ws;
  auto alloc = [&](size_t bytes) {
    char* r = p;
    p += (bytes + 255) & ~(size_t)255;
    return r;
  };
  float* scores1 = (float*)alloc((size_t)B_ * D_ * sizeof(float));
  int*   idx1    = (int*)  alloc((size_t)B_ * K1_ * sizeof(int));
  float* scores2 = (float*)alloc((size_t)B_ * H_ * sizeof(float));
  int*   idx2    = (int*)  alloc((size_t)B_ * K2_ * sizeof(int));
  __hip_bfloat16* h = (__hip_bfloat16*)alloc((size_t)B_ * N_ * H_ * sizeof(__hip_bfloat16));

  scores1_kernel<<<B_, 256, 0, stream>>>(x, ws1, scores1);
  topk_kernel<<<B_, 256, 0, stream>>>(scores1, D_, K1_, idx1);
  gemm1_kernel<<<dim3(H_ / 128, B_), 256, 0, stream>>>(x, idx1, W1, b1, ws2, h, scores2);
  topk_kernel<<<B_, 256, 0, stream>>>(scores2, H_, K2_, idx2);
  gemm2_kernel<<<dim3(D_ / 128, B_), 256, 0, stream>>>(h, idx2, W2, b2, out);
}

// Round 2
// 1908.659 us; speedup vs baseline: 3.5435x; 3.5435x over previous
//
#include <hip/hip_runtime.h>
#include <cstdint>
#include <cstddef>

#define B_  256
#define N_  128
#define D_  1024
#define H_  4096
#define K1_ 819
#define K2_ 3276
#define K1P 832      // 26 * 32
#define K2P 3296     // 103 * 32
#define KT1 (K1P / 32)
#define KT2 (K2P / 32)

typedef __bf16 bf16x8 __attribute__((ext_vector_type(8)));
typedef float floatx4 __attribute__((ext_vector_type(4)));

__device__ __forceinline__ unsigned short f2bf(float f) {
  unsigned u = __float_as_uint(f);
  u += 0x7FFFu + ((u >> 16) & 1u);   // RNE
  return (unsigned short)(u >> 16);
}
__device__ __forceinline__ float bf2f(unsigned short s) {
  return __uint_as_float(((unsigned)s) << 16);
}

// async global->LDS, 16B per lane; lds dest is wave-uniform base + lane*16
#define GL16(gp, lp) __builtin_amdgcn_global_load_lds( \
    (const __attribute__((address_space(1))) void*)(gp), \
    (__attribute__((address_space(3))) void*)(lp), 16, 0, 0)

// ---------------------------------------------------------------------------
// scores1[b,c] = sum_n x[b,n,c] * ws1[n], fp64 accumulate (selection-critical)
// ---------------------------------------------------------------------------
__global__ __launch_bounds__(256) void scores1_kernel(const float* __restrict__ x,
                                                      const float* __restrict__ ws1,
                                                      float* __restrict__ scores1) {
  int b = blockIdx.x, t = threadIdx.x;
  __shared__ float w[N_];
  if (t < N_) w[t] = ws1[t];
  __syncthreads();
  const float* xb = x + (size_t)b * N_ * D_;
  double a0 = 0, a1 = 0, a2 = 0, a3 = 0;
  for (int n = 0; n < N_; ++n) {
    double wv = (double)w[n];
    const float* r = xb + (size_t)n * D_ + t;
    a0 += (double)r[0]   * wv;
    a1 += (double)r[256] * wv;
    a2 += (double)r[512] * wv;
    a3 += (double)r[768] * wv;
  }
  float* s = scores1 + (size_t)b * D_ + t;
  s[0]   = (float)a0;
  s[256] = (float)a1;
  s[512] = (float)a2;
  s[768] = (float)a3;
}

// ---------------------------------------------------------------------------
// Exact top-K per row: 8-bit radix select + index-ordered compaction.
// ---------------------------------------------------------------------------
__global__ __launch_bounds__(256) void topk_kernel(const float* __restrict__ scores,
                                                   int C, int K,
                                                   int* __restrict__ idx_out) {
  int b = blockIdx.x, t = threadIdx.x;
  __shared__ unsigned keys[4096];
  __shared__ unsigned hist[256];
  __shared__ unsigned sbuf[256];
  __shared__ unsigned s_sel, s_want, s_bgt, s_beq;

  for (int c = t; c < C; c += 256) {
    unsigned u = __float_as_uint(scores[(size_t)b * C + c]);
    keys[c] = u ^ ((u & 0x80000000u) ? 0xFFFFFFFFu : 0x80000000u);
  }
  if (t == 0) { s_want = (unsigned)K; s_bgt = 0u; s_beq = 0u; }
  __syncthreads();

  unsigned prefix = 0;
  for (int shift = 24; shift >= 0; shift -= 8) {
    hist[t] = 0u;
    __syncthreads();
    unsigned mask = (shift == 24) ? 0u : (0xFFFFFFFFu << (shift + 8));
    for (int c = t; c < C; c += 256) {
      unsigned k = keys[c];
      if ((k & mask) == (prefix & mask))
        atomicAdd(&hist[(k >> shift) & 0xFFu], 1u);
    }
    __syncthreads();
    if (t == 0) {
      unsigned want = s_want, cum = 0u, sel = 0u;
      for (int d = 255; d >= 0; --d) {
        cum += hist[d];
        if (cum >= want) { sel = (unsigned)d; s_want = want - (cum - hist[d]); break; }
      }
      s_sel = sel;
    }
    __syncthreads();
    prefix |= (s_sel << shift);
  }
  unsigned kth = prefix;
  unsigned n_eq_keep = s_want;
  __syncthreads();

  int nch = C >> 8;
  for (int ch = 0; ch < nch; ++ch) {
    int c = (ch << 8) + t;
    unsigned k = keys[c];
    unsigned gt = (k > kth) ? 1u : 0u;
    unsigned eq = (k == kth) ? 1u : 0u;
    unsigned val = gt | (eq << 16);
    sbuf[t] = val;
    __syncthreads();
    unsigned incl = val;
    for (int off = 1; off < 256; off <<= 1) {
      unsigned o = (t >= off) ? sbuf[t - off] : 0u;
      __syncthreads();
      incl += o;
      sbuf[t] = incl;
      __syncthreads();
    }
    unsigned excl = incl - val;
    unsigned gt_ex = excl & 0xFFFFu, eq_ex = excl >> 16;
    unsigned base_gt = s_bgt, base_eq = s_beq;
    unsigned eq_before = base_eq + eq_ex;
    bool keep = (gt != 0u) || ((eq != 0u) && (eq_before < n_eq_keep));
    unsigned kept_eq_before = (eq_before < n_eq_keep) ? eq_before : n_eq_keep;
    unsigned pos = base_gt + gt_ex + kept_eq_before;
    if (keep) idx_out[(size_t)b * K + pos] = c;
    __syncthreads();
    if (t == 255) {
      s_bgt = base_gt + (incl & 0xFFFFu);
      s_beq = base_eq + (incl >> 16);
    }
    __syncthreads();
  }
}

// ---------------------------------------------------------------------------
// Prep: gather + hi/lo bf16 split of x into xch/xcl [B][N][K1P]
// ---------------------------------------------------------------------------
__global__ __launch_bounds__(256) void xprep_kernel(const float* __restrict__ x,
                                                    const int* __restrict__ idx1,
                                                    unsigned short* __restrict__ xch,
                                                    unsigned short* __restrict__ xcl) {
  int bn = blockIdx.x;
  int b = bn >> 7;
  const int* idxb = idx1 + (size_t)b * K1_;
  const float* xr = x + (size_t)bn * D_;
  unsigned short* oh = xch + (size_t)bn * K1P;
  unsigned short* ol = xcl + (size_t)bn * K1P;
  for (int j = threadIdx.x; j < K1P; j += 256) {
    float v = (j < K1_) ? xr[idxb[j]] : 0.f;
    unsigned short hi = f2bf(v);
    unsigned short lo = f2bf(v - bf2f(hi));
    oh[j] = hi;
    ol[j] = lo;
  }
}

// hi/lo split of W1 [H][K1] -> [H][K1P]
__global__ __launch_bounds__(256) void w1split_kernel(const float* __restrict__ W1,
                                                      unsigned short* __restrict__ w1h,
                                                      unsigned short* __restrict__ w1l) {
  int e = blockIdx.x * 256 + threadIdx.x;
  int k = e % K1P, row = e / K1P;
  float v = (k < K1_) ? W1[(size_t)row * K1_ + k] : 0.f;
  unsigned short hi = f2bf(v);
  unsigned short lo = f2bf(v - bf2f(hi));
  w1h[e] = hi;
  w1l[e] = lo;
}

// bf16 convert of W2 [D][K2] -> [D][K2P]
__global__ __launch_bounds__(256) void w2conv_kernel(const float* __restrict__ W2,
                                                     unsigned short* __restrict__ w2b) {
  int e = blockIdx.x * 256 + threadIdx.x;
  int k = e % K2P, row = e / K2P;
  w2b[e] = (k < K2_) ? f2bf(W2[(size_t)row * K2_ + k]) : (unsigned short)0;
}

// gather h [B][N][H] bf16 -> hcomp [B][N][K2P] bf16
__global__ __launch_bounds__(256) void hcompact_kernel(const unsigned short* __restrict__ h,
                                                       const int* __restrict__ idx2,
                                                       unsigned short* __restrict__ hcomp) {
  int bn = blockIdx.x;
  int b = bn >> 7;
  const int* idxb = idx2 + (size_t)b * K2_;
  const unsigned short* hr = h + (size_t)bn * H_;
  unsigned short* o = hcomp + (size_t)bn * K2P;
  for (int j = threadIdx.x; j < K2P; j += 256)
    o[j] = (j < K2_) ? hr[idxb[j]] : (unsigned short)0;
}

// ---------------------------------------------------------------------------
// GEMM1: h = relu(xc * W1^T + b1) via bf16x3 split MFMA (fp32-grade accuracy);
// bf16 h store + fused scores2 epilogue.
// Tile 128(n) x 128(hc) x BK32; fragment-order LDS layout (conflict-free).
// LDS chunk c (16B) <-> global row=((c>>6)<<4)|(c&15), kofs=((c>>4)&3)*8.
// ---------------------------------------------------------------------------
__global__ __launch_bounds__(256) void gemm1_kernel(
    const unsigned short* __restrict__ xch, const unsigned short* __restrict__ xcl,
    const unsigned short* __restrict__ w1h, const unsigned short* __restrict__ w1l,
    const float* __restrict__ b1, const float* __restrict__ ws2,
    unsigned short* __restrict__ h, float* __restrict__ scores2) {
  const int b = blockIdx.y, hc0 = blockIdx.x * 128;
  const int t = threadIdx.x, w = t >> 6, lane = t & 63;
  const int ml = lane & 15, qd = lane >> 4;
  __shared__ unsigned short Ah[4096], Al[4096], Bh[4096], Bl[4096];
  __shared__ float ws2s[128];
  __shared__ float scred[4][64];
  if (t < 128) ws2s[t] = ws2[t];

  floatx4 acc[4][4] = {};

  const unsigned short* Abh = xch + (size_t)b * N_ * K1P;
  const unsigned short* Abl = xcl + (size_t)b * N_ * K1P;
  const unsigned short* Bbh = w1h + (size_t)hc0 * K1P;
  const unsigned short* Bbl = w1l + (size_t)hc0 * K1P;

  const int c0 = w * 64 + lane, c1 = c0 + 256;
  const size_t off0 = (size_t)(((c0 >> 6) << 4) | (c0 & 15)) * K1P + (size_t)(((c0 >> 4) & 3) * 8);
  const size_t off1 = (size_t)(((c1 >> 6) << 4) | (c1 & 15)) * K1P + (size_t)(((c1 >> 4) & 3) * 8);
  const int lb0 = w * 512, lb1 = 2048 + w * 512;  // ushort offsets, wave-uniform

  int aoff[4], boff[4];
#pragma unroll
  for (int i = 0; i < 4; ++i) {
    aoff[i] = ((((w >> 1) * 4 + i) * 64) + qd * 16 + ml) * 8;
    boff[i] = ((((w & 1) * 4 + i) * 64) + qd * 16 + ml) * 8;
  }

  for (int kt = 0; kt < KT1; ++kt) {
    const int k0 = kt * 32;
    __syncthreads();
    GL16(Abh + off0 + k0, &Ah[lb0]);
    GL16(Abh + off1 + k0, &Ah[lb1]);
    GL16(Abl + off0 + k0, &Al[lb0]);
    GL16(Abl + off1 + k0, &Al[lb1]);
    GL16(Bbh + off0 + k0, &Bh[lb0]);
    GL16(Bbh + off1 + k0, &Bh[lb1]);
    GL16(Bbl + off0 + k0, &Bl[lb0]);
    GL16(Bbl + off1 + k0, &Bl[lb1]);
    __syncthreads();
    bf16x8 ah[4], al[4];
#pragma unroll
    for (int i = 0; i < 4; ++i) {
      ah[i] = *(const bf16x8*)&Ah[aoff[i]];
      al[i] = *(const bf16x8*)&Al[aoff[i]];
    }
#pragma unroll
    for (int j = 0; j < 4; ++j) {
      const bf16x8 bh = *(const bf16x8*)&Bh[boff[j]];
      const bf16x8 bl = *(const bf16x8*)&Bl[boff[j]];
#pragma unroll
      for (int i = 0; i < 4; ++i) {
        acc[i][j] = __builtin_amdgcn_mfma_f32_16x16x32_bf16(ah[i], bh, acc[i][j], 0, 0, 0);
        acc[i][j] = __builtin_amdgcn_mfma_f32_16x16x32_bf16(ah[i], bl, acc[i][j], 0, 0, 0);
        acc[i][j] = __builtin_amdgcn_mfma_f32_16x16x32_bf16(al[i], bh, acc[i][j], 0, 0, 0);
      }
    }
  }

  // epilogue: bias+relu, bf16 h store, scores2 reduction
  const int wr0 = (w >> 1) * 64, wc0 = (w & 1) * 64;
  float bias[4], sc[4] = {0.f, 0.f, 0.f, 0.f};
#pragma unroll
  for (int j = 0; j < 4; ++j) bias[j] = b1[hc0 + wc0 + j * 16 + ml];
#pragma unroll
  for (int i = 0; i < 4; ++i) {
#pragma unroll
    for (int r = 0; r < 4; ++r) {
      const int n = wr0 + i * 16 + qd * 4 + r;
      const float wsn = ws2s[n];
      unsigned short* hp = h + ((size_t)(b * N_ + n)) * H_ + hc0 + wc0;
#pragma unroll
      for (int j = 0; j < 4; ++j) {
        float v = acc[i][j][r] + bias[j];
        v = fmaxf(v, 0.f);
        hp[j * 16 + ml] = f2bf(v);
        sc[j] += v * wsn;
      }
    }
  }
#pragma unroll
  for (int j = 0; j < 4; ++j) {
    sc[j] += __shfl_xor(sc[j], 16);
    sc[j] += __shfl_xor(sc[j], 32);
  }
  if (lane < 16) {
#pragma unroll
    for (int j = 0; j < 4; ++j) scred[w][j * 16 + lane] = sc[j];
  }
  __syncthreads();
  if (t < 128) {
    const int c = t & 63, hi2 = t >> 6;
    scores2[(size_t)b * H_ + hc0 + t] = scred[hi2][c] + scred[hi2 + 2][c];
  }
}

// ---------------------------------------------------------------------------
// GEMM2: out = hcomp * W2^T + b2, single bf16 MFMA, fp32 out.
// ---------------------------------------------------------------------------
__global__ __launch_bounds__(256) void gemm2_kernel(
    const unsigned short* __restrict__ hcomp, const unsigned short* __restrict__ w2b,
    const float* __restrict__ b2, float* __restrict__ out) {
  const int b = blockIdx.y, d0 = blockIdx.x * 128;
  const int t = threadIdx.x, w = t >> 6, lane = t & 63;
  const int ml = lane & 15, qd = lane >> 4;
  __shared__ unsigned short Ah[4096], Bh[4096];

  floatx4 acc[4][4] = {};

  const unsigned short* Ab = hcomp + (size_t)b * N_ * K2P;
  const unsigned short* Bb = w2b + (size_t)d0 * K2P;

  const int c0 = w * 64 + lane, c1 = c0 + 256;
  const size_t off0 = (size_t)(((c0 >> 6) << 4) | (c0 & 15)) * K2P + (size_t)(((c0 >> 4) & 3) * 8);
  const size_t off1 = (size_t)(((c1 >> 6) << 4) | (c1 & 15)) * K2P + (size_t)(((c1 >> 4) & 3) * 8);
  const int lb0 = w * 512, lb1 = 2048 + w * 512;

  int aoff[4], boff[4];
#pragma unroll
  for (int i = 0; i < 4; ++i) {
    aoff[i] = ((((w >> 1) * 4 + i) * 64) + qd * 16 + ml) * 8;
    boff[i] = ((((w & 1) * 4 + i) * 64) + qd * 16 + ml) * 8;
  }

  for (int kt = 0; kt < KT2; ++kt) {
    const int k0 = kt * 32;
    __syncthreads();
    GL16(Ab + off0 + k0, &Ah[lb0]);
    GL16(Ab + off1 + k0, &Ah[lb1]);
    GL16(Bb + off0 + k0, &Bh[lb0]);
    GL16(Bb + off1 + k0, &Bh[lb1]);
    __syncthreads();
    bf16x8 ah[4];
#pragma unroll
    for (int i = 0; i < 4; ++i) ah[i] = *(const bf16x8*)&Ah[aoff[i]];
#pragma unroll
    for (int j = 0; j < 4; ++j) {
      const bf16x8 bh = *(const bf16x8*)&Bh[boff[j]];
#pragma unroll
      for (int i = 0; i < 4; ++i)
        acc[i][j] = __builtin_amdgcn_mfma_f32_16x16x32_bf16(ah[i], bh, acc[i][j], 0, 0, 0);
    }
  }

  const int wr0 = (w >> 1) * 64, wc0 = (w & 1) * 64;
  float bias[4];
#pragma unroll
  for (int j = 0; j < 4; ++j) bias[j] = b2[d0 + wc0 + j * 16 + ml];
#pragma unroll
  for (int i = 0; i < 4; ++i) {
#pragma unroll
    for (int r = 0; r < 4; ++r) {
      const int n = wr0 + i * 16 + qd * 4 + r;
      float* op = out + ((size_t)(b * N_ + n)) * D_ + d0 + wc0;
#pragma unroll
      for (int j = 0; j < 4; ++j)
        op[j * 16 + ml] = acc[i][j][r] + bias[j];
    }
  }
}

// ---------------------------------------------------------------------------
extern "C" void kernel_launch(void* const* d_in, const int* in_sizes, int n_in,
                              void* d_out, int out_size, void* d_ws, size_t ws_size,
                              hipStream_t stream) {
  (void)in_sizes; (void)n_in; (void)out_size; (void)ws_size;
  const float* x   = (const float*)d_in[0];
  const float* ws1 = (const float*)d_in[1];
  const float* W1  = (const float*)d_in[3];
  const float* b1  = (const float*)d_in[4];
  const float* ws2 = (const float*)d_in[5];
  const float* W2  = (const float*)d_in[7];
  const float* b2  = (const float*)d_in[8];
  float* out = (float*)d_out;

  char* p = (char*)d_ws;
  auto alloc = [&](size_t bytes) {
    char* r = p;
    p += (bytes + 255) & ~(size_t)255;
    return r;
  };
  float* scores1 = (float*)alloc((size_t)B_ * D_ * sizeof(float));
  int*   idx1    = (int*)  alloc((size_t)B_ * K1_ * sizeof(int));
  float* scores2 = (float*)alloc((size_t)B_ * H_ * sizeof(float));
  int*   idx2    = (int*)  alloc((size_t)B_ * K2_ * sizeof(int));
  unsigned short* w1h = (unsigned short*)alloc((size_t)H_ * K1P * sizeof(short));
  unsigned short* w1l = (unsigned short*)alloc((size_t)H_ * K1P * sizeof(short));
  unsigned short* w2b = (unsigned short*)alloc((size_t)D_ * K2P * sizeof(short));
  unsigned short* h   = (unsigned short*)alloc((size_t)B_ * N_ * H_ * sizeof(short));
  // region shared by {xch, xcl} (live through gemm1) and hcomp (live after)
  size_t xc_bytes    = (size_t)B_ * N_ * K1P * sizeof(short);   // 54.5 MB each
  size_t hcomp_bytes = (size_t)B_ * N_ * K2P * sizeof(short);   // 216 MB
  char* region = alloc(hcomp_bytes > 2 * xc_bytes ? hcomp_bytes : 2 * xc_bytes);
  unsigned short* xch   = (unsigned short*)region;
  unsigned short* xcl   = (unsigned short*)(region + xc_bytes);
  unsigned short* hcomp = (unsigned short*)region;  // aliases xc after gemm1 (stream-ordered)

  scores1_kernel<<<B_, 256, 0, stream>>>(x, ws1, scores1);
  topk_kernel<<<B_, 256, 0, stream>>>(scores1, D_, K1_, idx1);
  xprep_kernel<<<B_ * N_, 256, 0, stream>>>(x, idx1, xch, xcl);
  w1split_kernel<<<(H_ * K1P) / 256, 256, 0, stream>>>(W1, w1h, w1l);
  w2conv_kernel<<<(D_ * K2P) / 256, 256, 0, stream>>>(W2, w2b);
  gemm1_kernel<<<dim3(H_ / 128, B_), 256, 0, stream>>>(xch, xcl, w1h, w1l, b1, ws2, h, scores2);
  topk_kernel<<<B_, 256, 0, stream>>>(scores2, H_, K2_, idx2);
  hcompact_kernel<<<B_ * N_, 256, 0, stream>>>(h, idx2, hcomp);
  gemm2_kernel<<<dim3(D_ / 128, B_), 256, 0, stream>>>(hcomp, w2b, b2, out);
}